// Round 13
// baseline (300.151 us; speedup 1.0000x reference)
//
#include <hip/hip_runtime.h>

// pred/target (4,4,64,128,128) fp32 -> 16 volumes of 64x128x128.
#define NB 16
#define DD 64
#define HH 128
#define WW 128
#define HW (HH * WW)

constexpr int RW  = 4;             // output rows per wave
constexpr int LYW = RW + 2;        // 6 slab rows
constexpr int SLOT = LYW * WW;     // 768 floats per ring slot (3 KB)
constexpr int CDW = 32;            // output planes per wave (D-half)
constexpr int NKW = CDW + 2;       // 34 input planes per wave
constexpr float INV_COUNT = 1.0f / 50331648.0f; // 1/(3*16*64*128*128)

__global__ void zero_out_kernel(float* out) {
    if (threadIdx.x == 0 && blockIdx.x == 0) out[0] = 0.0f;
}

__global__ __launch_bounds__(256) void sobel_l1_kernel(
    const float* __restrict__ pred,
    const float* __restrict__ target,
    float* __restrict__ out)
{
    // Wave-private 3-slab plane ring -> ZERO barriers in the main loop.
    __shared__ float S[4][3][SLOT];    // 36 KB
    __shared__ float wsum[4];

    const int tid  = threadIdx.x;
    const int wv   = tid >> 6;         // wave 0..3: hc = wv&1, dq = wv>>1
    const int lane = tid & 63;
    int b = blockIdx.x;                // 256 blocks: 16 h-groups x 16 volumes
    const int bh = b & 15; b >>= 4;
    const int bn = b;

    const int hc = wv & 1, dq = wv >> 1;
    const int h0w   = bh * 8 + hc * RW;   // wave's first output row
    const int dbase = dq * CDW;           // input plane k -> gd = dbase-1+k
    const size_t nbase = (size_t)bn * (size_t)(DD * HW);

    // ---- staging constants: 192 float4/plane over 64 lanes = 3 slots ----
    int  soff[3];
    bool sokh[3];
#pragma unroll
    for (int j = 0; j < 3; ++j) {
        const int s  = j * 64 + lane;  // 0..191
        const int y  = s >> 5;         // 0..5 slab row
        const int q4 = s & 31;
        const int gh = h0w - 1 + y;
        sokh[j] = (unsigned)gh < HH;
        soff[j] = min(max(gh, 0), HH - 1) * WW + 4 * q4;
    }

    float4 sp[2][3], sq[2][3];         // 2-plane-deep prefetch staging

    auto load_st = [&](int k, int set) {
        const int gd  = dbase - 1 + k;
        const int gdc = min(max(gd, 0), DD - 1);
        const size_t pb = nbase + (size_t)gdc * HW;
#pragma unroll
        for (int j = 0; j < 3; ++j) {
            sp[set][j] = *(const float4*)(pred   + pb + soff[j]);
            sq[set][j] = *(const float4*)(target + pb + soff[j]);
        }
    };

    auto store_st = [&](int k, int set) {
        const int gd = dbase - 1 + k;
        const bool zok = (unsigned)gd < DD;
        float* B = S[wv][k % 3];
#pragma unroll
        for (int j = 0; j < 3; ++j) {
            const float m = (zok && sokh[j]) ? 1.0f : 0.0f;
            const float4 p = sp[set][j], q = sq[set][j];
            *(float4*)&B[4 * (j * 64 + lane)] =
                float4{(p.x - q.x) * m, (p.y - q.y) * m,
                       (p.z - q.z) * m, (p.w - q.w) * m};
        }
    };

    const int tc  = lane & 31;         // w-quad
    const int sub = lane >> 5;         // 0..1 -> output rows 2*sub, 2*sub+1

    float4 rA[2][3], rBh[2][3], rBw[2][3];  // per-output-row partial rings

    auto planeP = [&](int k) {
        const float* B = S[wv][k % 3];
        float4 rs[4], rdw[4];
#pragma unroll
        for (int r = 0; r < 4; ++r) {       // slab rows 2*sub .. 2*sub+3
            const float4 v = *(const float4*)&B[(2 * sub + r) * WW + 4 * tc];
            float lm = __shfl_up(v.w, 1, 32);   // width 32: halves separate
            float rp = __shfl_down(v.x, 1, 32);
            if (tc == 0)  lm = 0.f;
            if (tc == 31) rp = 0.f;
            rs[r]  = float4{lm  + 2.f * v.x + v.y,
                            v.x + 2.f * v.y + v.z,
                            v.y + 2.f * v.z + v.w,
                            v.z + 2.f * v.w + rp};
            rdw[r] = float4{v.y - lm, v.z - v.x, v.w - v.y, rp - v.z};
        }
        const int j = k % 3;
#pragma unroll
        for (int o = 0; o < 2; ++o) {
            rA[o][j]  = float4{rs[o].x + 2.f * rs[o+1].x + rs[o+2].x,
                               rs[o].y + 2.f * rs[o+1].y + rs[o+2].y,
                               rs[o].z + 2.f * rs[o+1].z + rs[o+2].z,
                               rs[o].w + 2.f * rs[o+1].w + rs[o+2].w};
            rBh[o][j] = float4{rs[o+2].x - rs[o].x, rs[o+2].y - rs[o].y,
                               rs[o+2].z - rs[o].z, rs[o+2].w - rs[o].w};
            rBw[o][j] = float4{rdw[o].x + 2.f * rdw[o+1].x + rdw[o+2].x,
                               rdw[o].y + 2.f * rdw[o+1].y + rdw[o+2].y,
                               rdw[o].z + 2.f * rdw[o+1].z + rdw[o+2].z,
                               rdw[o].w + 2.f * rdw[o+1].w + rdw[o+2].w};
        }
    };

    // ---- prologue (2-plane prefetch depth) ----
    float acc = 0.0f;
    load_st(0, 0); load_st(1, 1);
    store_st(0, 0); load_st(2, 0);
    store_st(1, 1); load_st(3, 1);
    planeP(0); planeP(1);

    // ---- barrier-free plane-tick loop ----
    for (int t = 0; t < CDW; ++t) {
        const int set = t & 1;
        store_st(t + 2, set);              // slab (t+2)%3: last read planeP(t-1)
        if (t + 4 < NKW) load_st(t + 4, set);
        planeP(t + 2);
        const int s0 = t % 3, s1 = (t + 1) % 3, s2 = (t + 2) % 3;
#pragma unroll
        for (int o = 0; o < 2; ++o) {
            const float4 a0 = rA[o][s0],  a2 = rA[o][s2];
            const float4 b0 = rBh[o][s0], b1 = rBh[o][s1], b2 = rBh[o][s2];
            const float4 c0 = rBw[o][s0], c1 = rBw[o][s1], c2 = rBw[o][s2];
            acc += fabsf(a2.x - a0.x) + fabsf(a2.y - a0.y)
                 + fabsf(a2.z - a0.z) + fabsf(a2.w - a0.w);
            acc += fabsf(b0.x + 2.f * b1.x + b2.x) + fabsf(b0.y + 2.f * b1.y + b2.y)
                 + fabsf(b0.z + 2.f * b1.z + b2.z) + fabsf(b0.w + 2.f * b1.w + b2.w);
            acc += fabsf(c0.x + 2.f * c1.x + c2.x) + fabsf(c0.y + 2.f * c1.y + c2.y)
                 + fabsf(c0.z + 2.f * c1.z + c2.z) + fabsf(c0.w + 2.f * c1.w + c2.w);
        }
    }

    // ---- block reduction (the only barrier) ----
#pragma unroll
    for (int off = 32; off > 0; off >>= 1)
        acc += __shfl_down(acc, off, 64);
    if (lane == 0) wsum[wv] = acc;
    __syncthreads();
    if (tid == 0) {
        const float s = wsum[0] + wsum[1] + wsum[2] + wsum[3];
        atomicAdd(out, s * INV_COUNT);
    }
}

extern "C" void kernel_launch(void* const* d_in, const int* in_sizes, int n_in,
                              void* d_out, int out_size, void* d_ws, size_t ws_size,
                              hipStream_t stream) {
    const float* pred   = (const float*)d_in[0];
    const float* target = (const float*)d_in[1];
    float* out = (float*)d_out;

    zero_out_kernel<<<1, 64, 0, stream>>>(out);

    // 16 volumes * 16 h-groups = 256 blocks (1 per CU; waves self-pace)
    const int nblocks = NB * (HH / 8);
    sobel_l1_kernel<<<nblocks, 256, 0, stream>>>(pred, target, out);
}

// Round 14
// 232.452 us; speedup vs baseline: 1.2912x; 1.2912x over previous
//
#include <hip/hip_runtime.h>

// pred/target (4,4,64,128,128) fp32 -> 16 volumes of 64x128x128.
#define NB 16
#define DD 64
#define HH 128
#define WW 128
#define HW (HH * WW)

constexpr int TH  = 8;             // output rows per block
constexpr int LY  = TH + 2;        // 10 slab rows
constexpr int PL  = LY * WW;       // 1280 floats per plane-slab (5 KB)
constexpr int CDO = 8;             // output planes per block
constexpr int NK  = CDO + 2;       // 10 input planes per block
constexpr float INV_COUNT = 1.0f / 50331648.0f; // 1/(3*16*64*128*128)

// 16-byte async global->LDS DMA. LDS dest is wave-uniform base + lane*16.
#define GLOAD_LDS16(g, l)                                      \
    __builtin_amdgcn_global_load_lds(                          \
        (const __attribute__((address_space(1))) void*)(g),    \
        (__attribute__((address_space(3))) void*)(l), 16, 0, 0)

__global__ void init_kernel(float* out, float* zp, size_t wsbytes) {
    if (blockIdx.x == 0 && threadIdx.x == 0) out[0] = 0.0f;
    const size_t off = (size_t)threadIdx.x * 16;
    if (off + 16 <= wsbytes)                       // zero 4 KB zero-page
        *(float4*)((char*)zp + off) = float4{0.f, 0.f, 0.f, 0.f};
}

__global__ __launch_bounds__(256, 5) void sobel_l1_kernel(
    const float* __restrict__ pred,
    const float* __restrict__ target,
    const float* __restrict__ zp,
    float* __restrict__ out)
{
    // 3-slot plane ring, raw p and q slabs (subtract at read). 30720 B total
    // -> 5 blocks/CU by LDS.
    __shared__ float Sp[3][PL];
    __shared__ float Sq[3][PL];

    const int tid  = threadIdx.x;
    const int wv   = tid >> 6;
    const int lane = tid & 63;
    int b = blockIdx.x;                // 2048 blocks: 16 bh x 8 dq x 16 bn
    const int bh = b & 15; b >>= 4;
    const int dq = b & 7;  b >>= 3;
    const int bn = b;

    const int h0 = bh * TH;
    const int dbase = dq * CDO;        // input plane k -> gd = dbase-1+k
    const size_t nbase = (size_t)bn * (size_t)(DD * HW);

    // ---- per-wave DMA issue table: issues j = wv, wv+4, wv+8 (j<10).
    //      j<5: pred group j; j>=5: target group j-5. Group g covers linear
    //      float4 slots g*64+lane -> slab offset 256*g + 4*lane. ----
    bool iss_q[3];  int iss_grp[3];  int iss_off[3];  bool iss_okh[3];  int iss_zoff[3];
#pragma unroll
    for (int m = 0; m < 3; ++m) {
        const int j = wv + 4 * m;
        if (j < 10) {
            iss_q[m]   = (j >= 5);
            const int g = iss_q[m] ? j - 5 : j;
            iss_grp[m] = g;
            const int s  = g * 64 + lane;
            const int y  = s >> 5;          // slab row 0..9
            const int q4 = s & 31;
            const int gh = h0 - 1 + y;
            iss_okh[m]  = (unsigned)gh < HH;
            iss_off[m]  = min(max(gh, 0), HH - 1) * WW + 4 * q4;
            iss_zoff[m] = 4 * q4;
        }
    }

    auto dma_plane = [&](int k) {      // stage input plane k into slot k%3
        const int gd  = dbase - 1 + k;
        const bool zok = (unsigned)gd < DD;
        const size_t pb = nbase + (size_t)min(max(gd, 0), DD - 1) * HW;
        const int slot = k % 3;
#pragma unroll
        for (int m = 0; m < 3; ++m) {
            const int j = wv + 4 * m;
            if (j < 10) {              // wave-uniform guard
                const float* base = iss_q[m] ? target : pred;
                const bool ok = zok && iss_okh[m];           // per-lane
                const float* g = ok ? (base + pb + iss_off[m])
                                    : (zp + iss_zoff[m]);    // zero page
                float* l = iss_q[m] ? &Sq[slot][iss_grp[m] * 256]
                                    : &Sp[slot][iss_grp[m] * 256];
                GLOAD_LDS16(g, l);
            }
        }
    };

    const int tc = tid & 31;           // w-quad
    const int lh = tid >> 5;           // output row 0..7

    float4 rA[3], rBh[3], rBw[3];      // per-input-plane partial ring

    auto planeP = [&](int k) {
        const float* Bp = Sp[k % 3];
        const float* Bq = Sq[k % 3];
        float4 rs[3], rdw[3];
#pragma unroll
        for (int r = 0; r < 3; ++r) {
            const int o = (lh + r) * WW + 4 * tc;
            const float4 p = *(const float4*)&Bp[o];
            const float4 q = *(const float4*)&Bq[o];
            const float4 v = float4{p.x - q.x, p.y - q.y, p.z - q.z, p.w - q.w};
            float lm = __shfl_up(v.w, 1, 32);
            float rp = __shfl_down(v.x, 1, 32);
            if (tc == 0)  lm = 0.f;
            if (tc == 31) rp = 0.f;
            rs[r]  = float4{lm  + 2.f * v.x + v.y,
                            v.x + 2.f * v.y + v.z,
                            v.y + 2.f * v.z + v.w,
                            v.z + 2.f * v.w + rp};
            rdw[r] = float4{v.y - lm, v.z - v.x, v.w - v.y, rp - v.z};
        }
        const int j = k % 3;
        rA[j]  = float4{rs[0].x + 2.f * rs[1].x + rs[2].x,
                        rs[0].y + 2.f * rs[1].y + rs[2].y,
                        rs[0].z + 2.f * rs[1].z + rs[2].z,
                        rs[0].w + 2.f * rs[1].w + rs[2].w};
        rBh[j] = float4{rs[2].x - rs[0].x, rs[2].y - rs[0].y,
                        rs[2].z - rs[0].z, rs[2].w - rs[0].w};
        rBw[j] = float4{rdw[0].x + 2.f * rdw[1].x + rdw[2].x,
                        rdw[0].y + 2.f * rdw[1].y + rdw[2].y,
                        rdw[0].z + 2.f * rdw[1].z + rdw[2].z,
                        rdw[0].w + 2.f * rdw[1].w + rdw[2].w};
    };

    // ---- prologue: DMA planes 0..2, drain once, prime ring ----
    float acc = 0.0f;
    dma_plane(0); dma_plane(1); dma_plane(2);
    __syncthreads();
    planeP(0); planeP(1);

    // ---- plane-tick loop: barrier, then DMA t+3 gets a full tick in flight ----
    for (int t = 0; t < CDO; ++t) {
        __syncthreads();               // drains DMA(t+2); slot t%3 is 2 ticks cold
        if (t + 3 < NK) dma_plane(t + 3);   // -> slot t%3
        planeP(t + 2);                 // slot (t+2)%3, staged last tick
        const int s0 = t % 3, s1 = (t + 1) % 3, s2 = (t + 2) % 3;
        const float4 a0 = rA[s0],  a2 = rA[s2];
        const float4 b0 = rBh[s0], b1 = rBh[s1], b2 = rBh[s2];
        const float4 c0 = rBw[s0], c1 = rBw[s1], c2 = rBw[s2];
        acc += fabsf(a2.x - a0.x) + fabsf(a2.y - a0.y)
             + fabsf(a2.z - a0.z) + fabsf(a2.w - a0.w);
        acc += fabsf(b0.x + 2.f * b1.x + b2.x) + fabsf(b0.y + 2.f * b1.y + b2.y)
             + fabsf(b0.z + 2.f * b1.z + b2.z) + fabsf(b0.w + 2.f * b1.w + b2.w);
        acc += fabsf(c0.x + 2.f * c1.x + c2.x) + fabsf(c0.y + 2.f * c1.y + c2.y)
             + fabsf(c0.z + 2.f * c1.z + c2.z) + fabsf(c0.w + 2.f * c1.w + c2.w);
    }

    // ---- block reduction (Sp[0] reused as scratch after a barrier) ----
    __syncthreads();
#pragma unroll
    for (int off = 32; off > 0; off >>= 1)
        acc += __shfl_down(acc, off, 64);
    if (lane == 0) Sp[0][wv] = acc;
    __syncthreads();
    if (tid == 0) {
        const float s = Sp[0][0] + Sp[0][1] + Sp[0][2] + Sp[0][3];
        atomicAdd(out, s * INV_COUNT);
    }
}

extern "C" void kernel_launch(void* const* d_in, const int* in_sizes, int n_in,
                              void* d_out, int out_size, void* d_ws, size_t ws_size,
                              hipStream_t stream) {
    const float* pred   = (const float*)d_in[0];
    const float* target = (const float*)d_in[1];
    float* out = (float*)d_out;
    float* zp  = (float*)d_ws;         // 4 KB zero page (zeroed every launch)

    init_kernel<<<1, 256, 0, stream>>>(out, zp, ws_size);

    // 16 volumes * 8 d-runs * 16 h-tiles = 2048 blocks
    const int nblocks = NB * (DD / CDO) * (HH / TH);
    sobel_l1_kernel<<<nblocks, 256, 0, stream>>>(pred, target, zp, out);
}